// Round 7
// baseline (846.291 us; speedup 1.0000x reference)
//
#include <hip/hip_runtime.h>
#include <hip/hip_bf16.h>
#include <cstdint>

// LISTA: Z = eta(X@We^T + Z@S^T), 16 unrolled steps. B=16384, n=256, m=1024.
// 256x256-tile, 8 waves (2Mx4N), BK=64, 128 KiB double-buffered LDS (swz2
// XOR-swizzle, conflict-free), mfma 32x32x16, LDS-transposed bf16 epilogue.
// Each step computes C = [X,Z] @ [We,S]^T (K=1280, NT=20) - no fp32 B matrix.
// Round-7 vs round-6: MERGED 4-PHASE WINDOW (was 8). Rounds 2/4/6 all sat at
// 1458 cyc/phase = MFMA(516) + LDS-serve(~384) + FIXED ~550 overhead x 80
// phases. Halve phase count, double per-phase MFMA (16), amortize overhead:
//  P1 (tile a, QM0): rd a.Ah0(8)+a.Bh1->bf1(4); stage; WL4 (A only! B rides
//     behind); Q00(bf0); WL0 (free, B landed under Q00); Q01(bf1); VM8; bar.
//  P2 (a, QM1): rd a.Ah1(8); stage; WL0; Q10(bf0) Q11(bf1); TRAILING rd
//     b.Bh0->bf0 (1-phase lead); VM8; bar.
//  P3/P4: same for tile b (buf1), trailing rd c.Bh0 at P4.
// Stage ledger (4 loads/phase, batch at X: drained VM8 at X+2-end, first
// ds_read at X+3 - uniform lag-3): P1:[c.Bh0,b.Ah1] P2:[c.Ah0,c.Bh1]
// P3:[c.Ah1,d.Bh0] P4:[d.Ah0,d.Bh1]. All overwrites >=1 barrier after the
// region's last read (a.Bh0 last read prev-P4 trailing; b.Bh0 last read P2
// trailing, d.Bh0 staged P3 - barrier between). Last window: VM6/VM2/VM0.

typedef __attribute__((ext_vector_type(8))) short short8;    // 8 x bf16
typedef __attribute__((ext_vector_type(16))) float f32x16;   // 32x32 mfma acc

__device__ __forceinline__ void g2lds16(const void* g, void* l) {
    __builtin_amdgcn_global_load_lds(
        (const __attribute__((address_space(1))) uint32_t*)(uintptr_t)g,
        (__attribute__((address_space(3))) uint32_t*)(uintptr_t)l,
        16, 0, 0);
}

#define VM8  asm volatile("s_waitcnt vmcnt(8)" ::: "memory")
#define VM6  asm volatile("s_waitcnt vmcnt(6)" ::: "memory")
#define VM2  asm volatile("s_waitcnt vmcnt(2)" ::: "memory")
#define VM0  asm volatile("s_waitcnt vmcnt(0)" ::: "memory")
#define WL4  asm volatile("s_waitcnt lgkmcnt(4)" ::: "memory")
#define WL0  asm volatile("s_waitcnt lgkmcnt(0)" ::: "memory")
#define SGB  __builtin_amdgcn_sched_barrier(0)
#define NOPX ((void)0)

// A-frags into af: 2 m-frags x 4 k-slices from A-half HH of buffer CB.
#define LOAD_A(CB, HH) do { \
    const char* ap_ = &lds[CB][0][HH][0] + arow; \
    _Pragma("unroll") \
    for (int mf_ = 0; mf_ < 2; ++mf_) { \
        af[mf_][0] = *(const short8*)(ap_ + mf_*4096 + ck0); \
        af[mf_][1] = *(const short8*)(ap_ + mf_*4096 + ck1); \
        af[mf_][2] = *(const short8*)(ap_ + mf_*4096 + ck2); \
        af[mf_][3] = *(const short8*)(ap_ + mf_*4096 + ck3); \
    } } while (0)

// B-frag into set BF: 1 n-frag x 4 k-slices from B-half HH of buffer CB.
#define LOAD_B(CB, HH, BF) do { \
    const char* bp_ = &lds[CB][1][HH][0] + brow; \
    BF[0] = *(const short8*)(bp_ + ck0); \
    BF[1] = *(const short8*)(bp_ + ck1); \
    BF[2] = *(const short8*)(bp_ + ck2); \
    BF[3] = *(const short8*)(bp_ + ck3); \
} while (0)

// 8 MFMA: quadrant (QM,QN), 2 independent chains of 4.
#define MFMA8(QM, QN, BF) do { \
    _Pragma("unroll") \
    for (int kk_ = 0; kk_ < 4; ++kk_) \
    _Pragma("unroll") \
    for (int mf_ = 0; mf_ < 2; ++mf_) \
        acc[(QM)*2+mf_][(QN)] = __builtin_amdgcn_mfma_f32_32x32x16_bf16( \
            af[mf_][kk_], BF[kk_], acc[(QM)*2+mf_][(QN)], 0, 0, 0); \
} while (0)

// QM0 phase of tile in buffer CB: rd A-h0 + B-h1; counted WL4; Q00; WL0; Q01.
#define PHASE_Q0(CB, STG, VMW) do { \
    LOAD_A(CB, 0); LOAD_B(CB, 1, bf1); STG; \
    WL4; SGB; \
    __builtin_amdgcn_s_setprio(1); \
    MFMA8(0, 0, bf0); \
    WL0; SGB; \
    MFMA8(0, 1, bf1); \
    __builtin_amdgcn_s_setprio(0); \
    VMW; \
    __builtin_amdgcn_s_barrier(); SGB; \
} while (0)

// QM1 phase: rd A-h1; WL0; Q10+Q11; trailing rd next B-h0 -> bf0.
#define PHASE_Q1(CB, STG, TRAIL, VMW) do { \
    LOAD_A(CB, 1); STG; \
    WL0; SGB; \
    __builtin_amdgcn_s_setprio(1); \
    MFMA8(1, 0, bf0); \
    MFMA8(1, 1, bf1); \
    __builtin_amdgcn_s_setprio(0); \
    TRAIL; \
    VMW; \
    __builtin_amdgcn_s_barrier(); SGB; \
} while (0)

// Tiles 0..NTX-1 from (Ax,Wx), stride NTX*128 B; NTX.. from (Az,Wz), NTZ*128 B.
// C[i,j] = sum_k A[i,k]*W[j,k]; output eta(C) (bf16, or fp32 if LAST).
template<int NTX, int NTZ, bool LAST>
__global__ void __launch_bounds__(512, 2)
lista_step(const unsigned short* __restrict__ Ax,
           const unsigned short* __restrict__ Wx,
           const unsigned short* __restrict__ Az,
           const unsigned short* __restrict__ Wz,
           const float* __restrict__ theta,
           unsigned short* __restrict__ Zout,
           float* __restrict__ Fout)
{
    constexpr int NT  = NTX + NTZ;     // total K-tiles of 64
    constexpr int NI  = NT / 2;        // windows (2 K-tiles each)
    constexpr int KBX = NTX * 128;     // X/We row stride (bytes)
    constexpr int KBZ = NTZ * 128;     // Z/S  row stride (bytes)

    // [buf][A=0/B=1][half][16KB]; half = permuted 128-row group so each half
    // is read in exactly one phase (A: bit6 of row; B: bit5 of row).
    __shared__ __align__(128) char lds[2][2][2][16384];

    const int t    = threadIdx.x;      // 0..511
    const int lane = t & 63;
    const int wave = t >> 6;           // 0..7
    const int wm   = wave >> 2;        // 0..1  (M half)
    const int wn   = wave & 3;         // 0..3  (N quarter)
    const int bm   = blockIdx.x;       // 0..63
    const int bn   = blockIdx.y;       // 0..3

    const char* Xb = (const char*)Ax + (size_t)bm * 256 * KBX;
    const char* Wb = (const char*)Wx + (size_t)bn * 256 * KBX;
    const char* Zb = (const char*)Az + (size_t)bm * 256 * KBZ;
    const char* Sb = (const char*)Wz + (size_t)bn * 256 * KBZ;

    // staging: thread t, call c handles linear chunk I = c*512+t -> compacted
    // row rho = I>>3, slot = I&7; slot holds global k-chunk slot ^ swz2(rho),
    // swz2(r) = (r ^ (r>>2)) & 7.
    const int u    = t >> 3;                       // 0..63
    const int gb16 = ((t & 7) ^ ((u ^ (u >> 2)) & 7)) << 4;
    const int rA0  = u;                            // A: row = rA0+64h (+128 c=1)
    const int rB0  = (u & 31) + 2 * (u & 32);      // B: row = rB0+32h (+128 c=1)

    // fragment-read constants (32x32x16: lane -> row=lane&31, k=(lane>>5)*8+e)
    const int r31  = lane & 31;
    const int l5   = lane >> 5;                    // k-half
    const int sw   = (r31 ^ (r31 >> 2)) & 7;       // swz2 of compacted row
    const int ck0  = ((0 + l5) ^ sw) << 4;
    const int ck1  = ((2 + l5) ^ sw) << 4;
    const int ck2  = ((4 + l5) ^ sw) << 4;
    const int ck3  = ((6 + l5) ^ sw) << 4;
    const int arow = (wm * 64 + r31) * 128;        // A compacted-row byte base
    const int brow = (wn * 32 + r31) * 128;        // B compacted-row byte base

    f32x16 acc[4][2];
#pragma unroll
    for (int i = 0; i < 4; ++i)
#pragma unroll
        for (int j = 0; j < 2; ++j)
#pragma unroll
            for (int r = 0; r < 16; ++r) acc[i][j][r] = 0.f;

    short8 af[2][4], bf0[4], bf1[4];

    auto STAGE_A = [&](int buf, int h, int kt) {
        const char* base; int kb, ko;
        if (NTZ == 0 || kt < NTX) { base = Xb; kb = KBX; ko = kt * 128; }
        else                      { base = Zb; kb = KBZ; ko = (kt - NTX) * 128; }
        char* lp = &lds[buf][0][h][0] + t * 16;
        const size_t go = (size_t)(rA0 + 64 * h) * kb + ko + gb16;
        g2lds16(base + go, lp);
        g2lds16(base + go + (size_t)128 * kb, lp + 8192);
    };
    auto STAGE_B = [&](int buf, int h, int kt) {
        const char* base; int kb, ko;
        if (NTZ == 0 || kt < NTX) { base = Wb; kb = KBX; ko = kt * 128; }
        else                      { base = Sb; kb = KBZ; ko = (kt - NTX) * 128; }
        char* lp = &lds[buf][1][h][0] + t * 16;
        const size_t go = (size_t)(rB0 + 32 * h) * kb + ko + gb16;
        g2lds16(base + go, lp);
        g2lds16(base + go + (size_t)128 * kb, lp + 8192);
    };

    // prologue: issue in lag-3 batch order [0Bh0][0Ah0][0Bh1] | [0Ah1,1Bh0] |
    // [1Ah0,1Bh1]; VM8 drains the first 6 (tile0's h0/Bh1 needed at preload/P1);
    // barrier; preload bf0 <- 0.Bh0 (4 lgkm, drained by P1's WL4).
    STAGE_B(0, 0, 0); STAGE_A(0, 0, 0); STAGE_B(0, 1, 0);
    STAGE_A(0, 1, 0); STAGE_B(1, 0, 1);
    STAGE_A(1, 0, 1); STAGE_B(1, 1, 1);
    VM8;
    __builtin_amdgcn_s_barrier(); SGB;
    LOAD_B(0, 0, bf0);

    // main loop: window it computes tiles a=2it (buf0, P1-P2) and b=2it+1
    // (buf1, P3-P4); stages c=2it+2, d=2it+3 per the lag-3 ledger. Uniform
    // VM8 at every phase end (12 outstanding -> 8, drains the batch whose
    // first ds_read is next phase).
#pragma unroll 1
    for (int it = 0; it < NI - 1; ++it) {
        const int b = 2 * it + 1, c = 2 * it + 2, d = 2 * it + 3;
        PHASE_Q0(0, (STAGE_B(0,0,c), STAGE_A(1,1,b)),              VM8);
        PHASE_Q1(0, (STAGE_A(0,0,c), STAGE_B(0,1,c)),
                    LOAD_B(1,0,bf0),                               VM8);
        PHASE_Q0(1, (STAGE_A(0,1,c), STAGE_B(1,0,d)),              VM8);
        PHASE_Q1(1, (STAGE_A(1,0,d), STAGE_B(1,1,d)),
                    LOAD_B(0,0,bf0),                               VM8);
    }
    {   // last window: only b.Ah1 left to stage; custom drains VM6/VM2/VM0.
        const int b = NT - 1;
        PHASE_Q0(0, STAGE_A(1,1,b), VM6);
        PHASE_Q1(0, NOPX, LOAD_B(1,0,bf0), VM2);
        PHASE_Q0(1, NOPX, VM0);
        PHASE_Q1(1, NOPX, NOPX, NOPX);
    }

    // epilogue. 32x32 C/D: col = lane&31, row = (reg&3)+8*(reg>>2)+4*(lane>>5)
    const int colb = bn * 256 + wn * 64 + r31;
    const int rowb = bm * 256 + wm * 128;
    const float th0 = theta[colb];
    const float th1 = theta[colb + 32];

    if constexpr (LAST) {
        // fp32 direct: 32 lanes x 4B = full 128B line per row-chunk.
#pragma unroll
        for (int MF = 0; MF < 4; ++MF)
#pragma unroll
        for (int reg = 0; reg < 16; ++reg) {
            const int rrow = rowb + MF * 32 + (reg & 3) + 8 * (reg >> 2) + 4 * l5;
#pragma unroll
            for (int h = 0; h < 2; ++h) {
                const float c = acc[MF][h][reg];
                const float a = fabsf(c) - (h ? th1 : th0);
                const float z = a > 0.f ? (c > 0.f ? a : -a) : 0.f;
                Fout[(size_t)rrow * 1024 + colb + h * 32] = z;
            }
        }
    } else {
        // bf16 via per-wave 16KB LDS transpose slab; readback row-linear ->
        // each global store = 8 rows x 128B full lines (no write RMW).
        char* slab = &lds[0][0][0][0] + wave * 16384;
#pragma unroll
        for (int MF = 0; MF < 4; ++MF)
#pragma unroll
        for (int h = 0; h < 2; ++h)
#pragma unroll
        for (int reg = 0; reg < 16; ++reg) {
            const int row = MF * 32 + (reg & 3) + 8 * (reg >> 2) + 4 * l5;
            const int cb  = (h * 64 + r31 * 2) ^ ((row & 7) << 4);
            const float c = acc[MF][h][reg];
            const float a = fabsf(c) - (h ? th1 : th0);
            const float z = a > 0.f ? (c > 0.f ? a : -a) : 0.f;
            __hip_bfloat16 hb = __float2bfloat16(z);
            *(unsigned short*)(slab + row * 128 + cb) = *(const unsigned short*)&hb;
        }
        SGB;
#pragma unroll
        for (int i = 0; i < 16; ++i) {
            const int r = i * 8 + (lane >> 3);
            const short8 v = *(const short8*)(slab + r * 128 + (((lane & 7) ^ (r & 7)) << 4));
            char* gp = (char*)Zout + (size_t)(rowb + r) * 2048
                     + bn * 512 + wn * 128 + (lane & 7) * 16;
            *(short8*)gp = v;
        }
    }
}

__global__ void __launch_bounds__(256)
cvt4(const float* __restrict__ s, unsigned short* __restrict__ d, int n4)
{
    const int i = blockIdx.x * blockDim.x + threadIdx.x;
    if (i < n4) {
        const float4 v = ((const float4*)s)[i];
        ushort4 o;
        __hip_bfloat16 b;
        b = __float2bfloat16(v.x); o.x = *(unsigned short*)&b;
        b = __float2bfloat16(v.y); o.y = *(unsigned short*)&b;
        b = __float2bfloat16(v.z); o.z = *(unsigned short*)&b;
        b = __float2bfloat16(v.w); o.w = *(unsigned short*)&b;
        ((ushort4*)d)[i] = o;
    }
}

extern "C" void kernel_launch(void* const* d_in, const int* in_sizes, int n_in,
                              void* d_out, int out_size, void* d_ws, size_t ws_size,
                              hipStream_t stream) {
    (void)in_sizes; (void)n_in; (void)out_size; (void)ws_size;
    const float* X     = (const float*)d_in[0];  // 16384 x 256
    const float* We    = (const float*)d_in[1];  // 1024 x 256
    const float* S     = (const float*)d_in[2];  // 1024 x 1024
    const float* theta = (const float*)d_in[3];  // 1024
    float* out = (float*)d_out;                  // 16384 x 1024 fp32

    char* ws = (char*)d_ws;
    unsigned short* S_bf  = (unsigned short*)(ws);                           //  2 MB
    unsigned short* X_bf  = (unsigned short*)(ws + (size_t)2  * 1048576);    //  8 MB
    unsigned short* We_bf = (unsigned short*)(ws + (size_t)10 * 1048576);    // 0.5 MB
    unsigned short* Za    = (unsigned short*)(ws + (size_t)11 * 1048576);    // 32 MB
    unsigned short* Zb    = (unsigned short*)(ws + (size_t)43 * 1048576);    // 32 MB (total 75 MB)

    cvt4<<<dim3(1024), dim3(256), 0, stream>>>(S,  S_bf,  1024 * 1024 / 4);
    cvt4<<<dim3(4096), dim3(256), 0, stream>>>(X,  X_bf,  16384 * 256 / 4);
    cvt4<<<dim3(256),  dim3(256), 0, stream>>>(We, We_bf, 1024 * 256 / 4);

    const dim3 grid(64, 4), blk(512);

    // Z0 = eta(X @ We^T)            (K = 256)
    lista_step<4, 0, false><<<grid, blk, 0, stream>>>(
        X_bf, We_bf, nullptr, nullptr, theta, Za, nullptr);

    // steps 1..15: Z = eta([X,Z] @ [We,S]^T)   (K = 1280), ping-pong bf16
    unsigned short* zin = Za;
    unsigned short* zout = Zb;
    for (int tstep = 1; tstep <= 15; ++tstep) {
        lista_step<4, 16, false><<<grid, blk, 0, stream>>>(
            X_bf, We_bf, zin, S_bf, theta, zout, nullptr);
        unsigned short* tmp = zin; zin = zout; zout = tmp;
    }
    // step 16: write fp32 output directly
    lista_step<4, 16, true><<<grid, blk, 0, stream>>>(
        X_bf, We_bf, zin, S_bf, theta, nullptr, out);
}